// Round 1
// baseline (3905.853 us; speedup 1.0000x reference)
//
#include <hip/hip_runtime.h>
#include <stdint.h>

#define SEQ   128
#define BATCH 32
#define NSB   4096   // SEQ*BATCH
#define NVOC  32000
#define NIN   1024
#define NHID  1024
#define NG    4096   // 4*NHID

typedef __attribute__((ext_vector_type(8))) short bf16x8;
typedef __attribute__((ext_vector_type(4))) float f32x4;

__device__ __forceinline__ unsigned short f2bf(float x) {
  unsigned int u = __float_as_uint(x);
  u += 0x7fffu + ((u >> 16) & 1u);           // RN-even
  return (unsigned short)(u >> 16);
}
__device__ __forceinline__ float bf2f(unsigned short b) {
  return __uint_as_float(((unsigned int)b) << 16);
}
__device__ __forceinline__ void split2(float x, unsigned short &hi, unsigned short &lo) {
  hi = f2bf(x);
  lo = f2bf(x - bf2f(hi));
}

__device__ __forceinline__ f32x4 mfma16(bf16x8 a, bf16x8 b, f32x4 c) {
  return __builtin_amdgcn_mfma_f32_16x16x32_bf16(a, b, c, 0, 0, 0);
}

// async global->LDS, 16B per lane; LDS dest must be wave-uniform base + lane*16
__device__ __forceinline__ void gll16(const void* g, void* l) {
  __builtin_amdgcn_global_load_lds((const __attribute__((address_space(1))) unsigned int*)g,
                                   (__attribute__((address_space(3))) unsigned int*)l,
                                   16, 0, 0);
}

// ---------------------------------------------------------------------------
// Pre-pass kernels
// ---------------------------------------------------------------------------

// embed gather + bf16 hi/lo split: x[r][c] = embed_w[ids[r]][c], r = s*32+b
__global__ void embed_split(const int* __restrict__ ids, const float* __restrict__ emb,
                            unsigned short* __restrict__ xhi, unsigned short* __restrict__ xlo)
{
  const int total = NSB * NIN / 4;  // float4 units
  for (int i = blockIdx.x * blockDim.x + threadIdx.x; i < total; i += gridDim.x * blockDim.x) {
    int r  = i >> 8;          // 256 float4 units per row (NIN/4)
    int cu = i & 255;
    int id = ids[r];
    float4 v = *(const float4*)(emb + (size_t)id * NIN + cu * 4);
    unsigned short h0,h1,h2,h3,l0,l1,l2,l3;
    split2(v.x,h0,l0); split2(v.y,h1,l1); split2(v.z,h2,l2); split2(v.w,h3,l3);
    size_t o = (size_t)r * NIN + cu * 4;
    *(ushort4*)(xhi + o) = make_ushort4(h0,h1,h2,h3);
    *(ushort4*)(xlo + o) = make_ushort4(l0,l1,l2,l3);
  }
}

// transpose + split: out[c][r] = in[r][c]; in is [R][Cc] f32, out is [Cc][R] bf16 hi/lo
__global__ void transpose_split(const float* __restrict__ in,
                                unsigned short* __restrict__ ohi, unsigned short* __restrict__ olo,
                                int R, int Cc)
{
  __shared__ float tile[32][33];
  int c0 = blockIdx.x * 32, r0 = blockIdx.y * 32;
  int tx = threadIdx.x & 31, ty = threadIdx.x >> 5;  // 32 x 8
  #pragma unroll
  for (int i = 0; i < 32; i += 8)
    tile[ty + i][tx] = in[(size_t)(r0 + ty + i) * Cc + c0 + tx];
  __syncthreads();
  #pragma unroll
  for (int i = 0; i < 32; i += 8) {
    float v = tile[tx][ty + i];
    unsigned short hi, lo; split2(v, hi, lo);
    size_t o = (size_t)(c0 + ty + i) * R + r0 + tx;
    ohi[o] = hi; olo[o] = lo;
  }
}

// elementwise split (no transpose), n multiple of 4
__global__ void split_mat(const float* __restrict__ in,
                          unsigned short* __restrict__ ohi, unsigned short* __restrict__ olo,
                          size_t n)
{
  size_t stride = (size_t)gridDim.x * blockDim.x * 4;
  for (size_t i = ((size_t)blockIdx.x * blockDim.x + threadIdx.x) * 4; i < n; i += stride) {
    float4 v = *(const float4*)(in + i);
    unsigned short h0,h1,h2,h3,l0,l1,l2,l3;
    split2(v.x,h0,l0); split2(v.y,h1,l1); split2(v.z,h2,l2); split2(v.w,h3,l3);
    *(ushort4*)(ohi + i) = make_ushort4(h0,h1,h2,h3);
    *(ushort4*)(olo + i) = make_ushort4(l0,l1,l2,l3);
  }
}

__global__ void init_state(const float* __restrict__ h0, const float* __restrict__ c0,
                           unsigned short* __restrict__ hhi, unsigned short* __restrict__ hlo,
                           float* __restrict__ cst)
{
  int i = blockIdx.x * 256 + threadIdx.x;
  if (i < BATCH * NHID) {
    split2(h0[i], hhi[i], hlo[i]);
    cst[i] = c0[i];
  }
}

__global__ void finalize(const unsigned short* __restrict__ hhi, const unsigned short* __restrict__ hlo,
                         const float* __restrict__ cst,
                         float* __restrict__ out_h, float* __restrict__ out_c)
{
  int i = blockIdx.x * 256 + threadIdx.x;
  if (i < BATCH * NHID) {
    out_h[i] = bf2f(hhi[i]) + bf2f(hlo[i]);
    out_c[i] = cst[i];
  }
}

// ---------------------------------------------------------------------------
// bf16x3 GEMM: C[M][N] = A[M][K] * B^T  (+ bias[col])
// A given as Ahi/Alo [M][K] bf16, B given as Bhi/Blo [N][K] bf16 (K contiguous).
// m97 structure: 128x128 block tile, 4 waves (2x2), 64x64/wave, K-step 32,
// global_load_lds width 16 staging.
// ---------------------------------------------------------------------------
__global__ __launch_bounds__(256, 2)
void gemm_bt_x3(const unsigned short* __restrict__ Ahi, const unsigned short* __restrict__ Alo,
                const unsigned short* __restrict__ Bhi, const unsigned short* __restrict__ Blo,
                const float* __restrict__ bias, float* __restrict__ C,
                int M, int N, int K)
{
  __shared__ unsigned short sm[4][128 * 32];  // Ahi, Alo, Bhi, Blo tiles (32 KB)
  const int tid  = threadIdx.x;
  const int nblk = N >> 7;
  const int bm   = blockIdx.x / nblk;
  const int bn   = blockIdx.x % nblk;
  const int lane = tid & 63, wave = tid >> 6;
  const int wr = (wave >> 1) * 64, wc = (wave & 1) * 64;

  f32x4 acc[4][4];
  #pragma unroll
  for (int mf = 0; mf < 4; mf++)
    #pragma unroll
    for (int nf = 0; nf < 4; nf++)
      acc[mf][nf] = (f32x4){0.f, 0.f, 0.f, 0.f};

  // staging: thread t covers 16B at row=t/4, k-off=(t%4)*8 (rows 0..63), plus rows 64..127
  const int srow  = tid >> 2;
  const int skoff = (tid & 3) * 8;
  const unsigned short* gsrc[4];
  gsrc[0] = Ahi + (size_t)(bm * 128 + srow) * K + skoff;
  gsrc[1] = Alo + (size_t)(bm * 128 + srow) * K + skoff;
  gsrc[2] = Bhi + (size_t)(bn * 128 + srow) * K + skoff;
  gsrc[3] = Blo + (size_t)(bn * 128 + srow) * K + skoff;

  const int fk = (lane >> 4) * 8;
  const int fr = lane & 15;

  for (int k0 = 0; k0 < K; k0 += 32) {
    __syncthreads();
    #pragma unroll
    for (int m = 0; m < 4; m++) {
      gll16(gsrc[m] + k0,            &sm[m][0] + tid * 8);         // rows 0..63
      gll16(gsrc[m] + 64 * K + k0,   &sm[m][0] + 2048 + tid * 8);  // rows 64..127
    }
    __syncthreads();  // drains vmcnt (global_load_lds) before use

    bf16x8 ah[4], al[4], bh[4], bl[4];
    #pragma unroll
    for (int mf = 0; mf < 4; mf++) {
      ah[mf] = *(const bf16x8*)&sm[0][(wr + mf * 16 + fr) * 32 + fk];
      al[mf] = *(const bf16x8*)&sm[1][(wr + mf * 16 + fr) * 32 + fk];
    }
    #pragma unroll
    for (int nf = 0; nf < 4; nf++) {
      bh[nf] = *(const bf16x8*)&sm[2][(wc + nf * 16 + fr) * 32 + fk];
      bl[nf] = *(const bf16x8*)&sm[3][(wc + nf * 16 + fr) * 32 + fk];
    }
    #pragma unroll
    for (int mf = 0; mf < 4; mf++)
      #pragma unroll
      for (int nf = 0; nf < 4; nf++) {
        acc[mf][nf] = mfma16(ah[mf], bh[nf], acc[mf][nf]);
        acc[mf][nf] = mfma16(al[mf], bh[nf], acc[mf][nf]);
        acc[mf][nf] = mfma16(ah[mf], bl[nf], acc[mf][nf]);
      }
  }

  // epilogue: D layout col=lane&15, row=(lane>>4)*4+r  [m89]
  const int fq = (lane >> 4) * 4;
  #pragma unroll
  for (int mf = 0; mf < 4; mf++)
    #pragma unroll
    for (int nf = 0; nf < 4; nf++) {
      size_t col = (size_t)bn * 128 + wc + nf * 16 + fr;
      float bv = bias[col];
      #pragma unroll
      for (int r = 0; r < 4; r++) {
        size_t row = (size_t)bm * 128 + wr + mf * 16 + fq + r;
        C[row * N + col] = acc[mf][nf][r] + bv;
      }
    }
}

// ---------------------------------------------------------------------------
// One LSTM step. Grid: 64 blocks x 256 threads. Block owns h-slice hh0=blockIdx*16.
// Wave w computes gate quadrant w (i,f,o,g) for [32 batch x 16 hh] via bf16x3 MFMA.
// h (hi/lo) staged in LDS in 256-k chunks with XOR swizzle (D=1024 stride is a
// 16-way bank conflict otherwise). Fused activation epilogue.
// ---------------------------------------------------------------------------
__global__ __launch_bounds__(256, 2)
void lstm_step(const unsigned short* __restrict__ hp_hi, const unsigned short* __restrict__ hp_lo,
               unsigned short* __restrict__ hn_hi, unsigned short* __restrict__ hn_lo,
               float* __restrict__ cst,
               const unsigned short* __restrict__ Ut_hi, const unsigned short* __restrict__ Ut_lo,
               const float* __restrict__ gpre,
               unsigned short* __restrict__ hs_hi, unsigned short* __restrict__ hs_lo,
               int t)
{
  __shared__ unsigned short hl[2][32 * 256];  // 32 KB: k-chunk of h (hi, lo), swizzled
  __shared__ float gl[4][32][16];             // gate tiles for epilogue

  const int tid = threadIdx.x, lane = tid & 63, wave = tid >> 6;
  const int hh0 = blockIdx.x * 16;
  const int col = wave * NHID + hh0 + (lane & 15);  // Ut row = gate column
  const unsigned short* bp_hi = Ut_hi + (size_t)col * NHID;
  const unsigned short* bp_lo = Ut_lo + (size_t)col * NHID;

  f32x4 acc0 = (f32x4){0.f,0.f,0.f,0.f};  // batch rows 0..15
  f32x4 acc1 = (f32x4){0.f,0.f,0.f,0.f};  // batch rows 16..31
  const int fr = lane & 15;
  const int fkb = (lane >> 4) * 8;

  for (int kc = 0; kc < NHID; kc += 256) {
    __syncthreads();
    // stage h[32][kc:kc+256] hi+lo into LDS (16B units), XOR-swizzled
    for (int u = tid; u < 2048; u += 256) {
      int m = u >> 10, v = u & 1023;
      int row = v >> 5, kunit = v & 31;
      const unsigned short* src = (m ? hp_lo : hp_hi) + row * NHID + kc + kunit * 8;
      int boff = (row * 512 + kunit * 16) ^ ((row & 7) << 4);
      *(bf16x8*)((char*)&hl[m][0] + boff) = *(const bf16x8*)src;
    }
    __syncthreads();
    #pragma unroll
    for (int k0 = 0; k0 < 256; k0 += 32) {
      int fk = k0 + fkb;
      bf16x8 bh = *(const bf16x8*)(bp_hi + kc + fk);
      bf16x8 bl = *(const bf16x8*)(bp_lo + kc + fk);
      int b0 = (fr * 512 + fk * 2) ^ ((fr & 7) << 4);
      int b1 = ((fr + 16) * 512 + fk * 2) ^ ((fr & 7) << 4);
      bf16x8 a0h = *(const bf16x8*)((char*)&hl[0][0] + b0);
      bf16x8 a0l = *(const bf16x8*)((char*)&hl[1][0] + b0);
      bf16x8 a1h = *(const bf16x8*)((char*)&hl[0][0] + b1);
      bf16x8 a1l = *(const bf16x8*)((char*)&hl[1][0] + b1);
      acc0 = mfma16(a0h, bh, acc0);
      acc0 = mfma16(a0l, bh, acc0);
      acc0 = mfma16(a0h, bl, acc0);
      acc1 = mfma16(a1h, bh, acc1);
      acc1 = mfma16(a1l, bh, acc1);
      acc1 = mfma16(a1h, bl, acc1);
    }
  }

  const int fq = (lane >> 4) * 4;
  #pragma unroll
  for (int r = 0; r < 4; r++) {
    gl[wave][fq + r][fr]      = acc0[r];
    gl[wave][16 + fq + r][fr] = acc1[r];
  }
  __syncthreads();

  // activation over 32b x 16hh cells
  for (int cell = tid; cell < 512; cell += 256) {
    int b = cell >> 4, hh = cell & 15;
    int hidx = hh0 + hh;
    size_t prow = (size_t)(t * BATCH + b) * NG;
    float gi = gl[0][b][hh] + gpre[prow + hidx];
    float gf = gl[1][b][hh] + gpre[prow + NHID + hidx];
    float go = gl[2][b][hh] + gpre[prow + 2 * NHID + hidx];
    float gg = gl[3][b][hh] + gpre[prow + 3 * NHID + hidx];
    float iv = 1.f / (1.f + expf(-gi));
    float fv = 1.f / (1.f + expf(-gf));
    float ov = 1.f / (1.f + expf(-go));
    float gv = tanhf(gg);
    int ci = b * NHID + hidx;
    float cn = fv * cst[ci] + iv * gv;
    cst[ci] = cn;
    float hv = ov * tanhf(cn);
    unsigned short hi, lo; split2(hv, hi, lo);
    hn_hi[ci] = hi; hn_lo[ci] = lo;
    size_t so = (size_t)(t * BATCH + b) * NHID + hidx;
    hs_hi[so] = hi; hs_lo[so] = lo;
  }
}

// ---------------------------------------------------------------------------
extern "C" void kernel_launch(void* const* d_in, const int* in_sizes, int n_in,
                              void* d_out, int out_size, void* d_ws, size_t ws_size,
                              hipStream_t stream) {
  const int*   ids  = (const int*)d_in[0];
  const float* h0   = (const float*)d_in[1];
  const float* c0   = (const float*)d_in[2];
  const float* embw = (const float*)d_in[3];
  const float* W    = (const float*)d_in[4];
  const float* U    = (const float*)d_in[5];
  const float* Bb   = (const float*)d_in[6];
  const float* dw   = (const float*)d_in[7];
  const float* db   = (const float*)d_in[8];
  float* out = (float*)d_out;

  char* p = (char*)d_ws;
  auto carve = [&](size_t n) { char* r = p; p += (n + 255) & ~(size_t)255; return r; };

  unsigned short* x_hi  = (unsigned short*)carve((size_t)NSB * NIN * 2);
  unsigned short* x_lo  = (unsigned short*)carve((size_t)NSB * NIN * 2);
  unsigned short* Wt_hi = (unsigned short*)carve((size_t)NG * NIN * 2);
  unsigned short* Wt_lo = (unsigned short*)carve((size_t)NG * NIN * 2);
  unsigned short* Ut_hi = (unsigned short*)carve((size_t)NG * NHID * 2);
  unsigned short* Ut_lo = (unsigned short*)carve((size_t)NG * NHID * 2);
  unsigned short* dw_hi = (unsigned short*)carve((size_t)NVOC * NHID * 2);
  unsigned short* dw_lo = (unsigned short*)carve((size_t)NVOC * NHID * 2);
  float*          gpre  = (float*)carve((size_t)NSB * NG * 4);
  unsigned short* hs_hi = (unsigned short*)carve((size_t)NSB * NHID * 2);
  unsigned short* hs_lo = (unsigned short*)carve((size_t)NSB * NHID * 2);
  unsigned short* hb_hi0 = (unsigned short*)carve((size_t)BATCH * NHID * 2);
  unsigned short* hb_lo0 = (unsigned short*)carve((size_t)BATCH * NHID * 2);
  unsigned short* hb_hi1 = (unsigned short*)carve((size_t)BATCH * NHID * 2);
  unsigned short* hb_lo1 = (unsigned short*)carve((size_t)BATCH * NHID * 2);
  float*          cst   = (float*)carve((size_t)BATCH * NHID * 4);

  if ((size_t)(p - (char*)d_ws) > ws_size) return;  // workspace too small: bail cleanly

  // pre-pass
  embed_split<<<2048, 256, 0, stream>>>(ids, embw, x_hi, x_lo);
  transpose_split<<<dim3(NG / 32, NIN / 32), 256, 0, stream>>>(W, Wt_hi, Wt_lo, NIN, NG);
  transpose_split<<<dim3(NG / 32, NHID / 32), 256, 0, stream>>>(U, Ut_hi, Ut_lo, NHID, NG);
  split_mat<<<4096, 256, 0, stream>>>(dw, dw_hi, dw_lo, (size_t)NVOC * NHID);
  init_state<<<(BATCH * NHID + 255) / 256, 256, 0, stream>>>(h0, c0, hb_hi0, hb_lo0, cst);

  // gates_pre = x @ W + B  for all timesteps
  gemm_bt_x3<<<(NSB / 128) * (NG / 128), 256, 0, stream>>>(
      x_hi, x_lo, Wt_hi, Wt_lo, Bb, gpre, NSB, NG, NIN);

  // recurrence
  unsigned short* hbh[2] = {hb_hi0, hb_hi1};
  unsigned short* hbl[2] = {hb_lo0, hb_lo1};
  for (int t = 0; t < SEQ; t++) {
    lstm_step<<<NHID / 16, 256, 0, stream>>>(
        hbh[t & 1], hbl[t & 1], hbh[(t + 1) & 1], hbl[(t + 1) & 1],
        cst, Ut_hi, Ut_lo, gpre, hs_hi, hs_lo, t);
  }

  // final state outputs (after 128 steps, state is in buffer 0)
  finalize<<<(BATCH * NHID + 255) / 256, 256, 0, stream>>>(
      hb_hi0, hb_lo0, cst, out + (size_t)NSB * NVOC, out + (size_t)NSB * NVOC + BATCH * NHID);

  // decoder: out[s*32+b][v] = hs . dec_w[v] + dec_b[v]
  gemm_bt_x3<<<(NSB / 128) * (NVOC / 128), 256, 0, stream>>>(
      hs_hi, hs_lo, dw_hi, dw_lo, db, out, NSB, NVOC, NHID);
}